// Round 1
// baseline (218.890 us; speedup 1.0000x reference)
//
#include <hip/hip_runtime.h>
#include <math.h>

#define B_TOTAL 1024
#define NCASES 4

// Per-sample Catmull-Rom coefficients, scattered to bank order.
// coef[b][n] such that  interp(P, b) = sum_n coef[b][n] * P[n]
__global__ void coef_kernel(const float* __restrict__ x, float* __restrict__ coef) {
    int b = blockIdx.x * blockDim.x + threadIdx.x;
    if (b >= B_TOTAL) return;
    float phase = x[b * 343 + 342];
    float ps = 4.0f * phase;            // in [0,4)
    int k1 = (int)ps;                   // trunc == floor for positive
    float mu = ps - (float)k1;          // jnp.mod(ps, 1.0)
    k1 &= 3;
    float mu2 = mu * mu, mu3 = mu2 * mu;
    float c0 = -0.5f * mu3 +        mu2 - 0.5f * mu;
    float c1 =  1.5f * mu3 - 2.5f * mu2 + 1.0f;
    float c2 = -1.5f * mu3 + 2.0f * mu2 + 0.5f * mu;
    float c3 =  0.5f * mu3 - 0.5f * mu2;
    float cc[4];
    cc[(k1 + 3) & 3] = c0;
    cc[k1]           = c1;
    cc[(k1 + 1) & 3] = c2;
    cc[(k1 + 2) & 3] = c3;
    *(float4*)&coef[b * 4] = make_float4(cc[0], cc[1], cc[2], cc[3]);
}

// Fused interp-GEMM layer:
//   Hout[b,o] = act( sum_n coef[b,n] * ( dot(W[n,o,:], Hin[b,:K]) + bias[n,o] ) )
// Block tile: 32 o  x 64 b, all 4 weight banks. Thread tile: 2o x 4b x 4n accs.
// Double-buffered LDS staging (one barrier per K-chunk of 16).
template<bool ELU>
__global__ __launch_bounds__(256) void layer_kernel(
    const float* __restrict__ W,     // (4, O, K)
    const float* __restrict__ bias,  // (4, O)
    const float* __restrict__ Hin,   // (1024, ld) ; use first K columns
    int ld, int K, int O,
    const float* __restrict__ coef,  // (1024, 4)
    float* __restrict__ Hout)        // (1024, O)
{
    constexpr int KC = 16;
    __shared__ float w_lds[2][NCASES * KC * 34];  // [n][k][o], stride 34 (pad)
    __shared__ float h_lds[2][KC * 68];           // [k][b],    stride 68 (pad)

    const int tid = threadIdx.x;
    const int o0 = blockIdx.x * 32;
    const int b0 = blockIdx.y * 64;

    const int to = tid & 15;   // o-group: o = o0 + to*2 + {0,1}
    const int tb = tid >> 4;   // b-group: b = b0 + tb*4 + {0..3}

    // W staging mapping: t = wn*64 + woq*16 + wkq
    const int wn  = tid >> 6;         // bank 0..3
    const int wr  = tid & 63;
    const int wkq = wr & 15;          // k within chunk
    const int woq = wr >> 4;          // 0..3 ; o_local = woq*8 + i (i=0..7)

    // H staging mapping: b_local = tid>>2, k = (tid&3)*4 + i
    const int hb = tid >> 2;
    const int hk = (tid & 3) * 4;

    const float* wbase = W + (size_t)(wn * O + o0 + woq * 8) * K + wkq;
    const float* hbase = Hin + (size_t)(b0 + hb) * ld + hk;

    float acc[NCASES][2][4];
    #pragma unroll
    for (int n = 0; n < NCASES; n++)
        #pragma unroll
        for (int i = 0; i < 2; i++)
            #pragma unroll
            for (int j = 0; j < 4; j++) acc[n][i][j] = 0.f;

    const int nchunks = (K + KC - 1) / KC;

    float wreg[8], hreg[4];
    // --- prologue: load + store chunk 0 ---
    #pragma unroll
    for (int i = 0; i < 8; i++) {
        bool ok = (wkq < K) && ((o0 + woq * 8 + i) < O);
        wreg[i] = ok ? wbase[(size_t)i * K] : 0.f;
    }
    #pragma unroll
    for (int i = 0; i < 4; i++) {
        hreg[i] = ((hk + i) < K) ? hbase[i] : 0.f;
    }
    #pragma unroll
    for (int i = 0; i < 8; i++) w_lds[0][(wn * KC + wkq) * 34 + woq * 8 + i] = wreg[i];
    #pragma unroll
    for (int i = 0; i < 4; i++) h_lds[0][(hk + i) * 68 + hb] = hreg[i];
    __syncthreads();

    for (int c = 0; c < nchunks; c++) {
        const int cur = c & 1;
        const bool more = (c + 1) < nchunks;
        if (more) {  // prefetch next chunk into registers (overlaps compute)
            const int kg = (c + 1) * KC + wkq;
            #pragma unroll
            for (int i = 0; i < 8; i++) {
                bool ok = (kg < K) && ((o0 + woq * 8 + i) < O);
                wreg[i] = ok ? wbase[(size_t)i * K + (c + 1) * KC] : 0.f;
            }
            #pragma unroll
            for (int i = 0; i < 4; i++) {
                int k = (c + 1) * KC + hk + i;
                hreg[i] = (k < K) ? hbase[(c + 1) * KC + i] : 0.f;
            }
        }
        const float* wl = w_lds[cur];
        const float* hl = h_lds[cur];
        #pragma unroll
        for (int k = 0; k < KC; k++) {
            float4 h = *(const float4*)&hl[k * 68 + tb * 4];
            #pragma unroll
            for (int n = 0; n < NCASES; n++) {
                float2 w = *(const float2*)&wl[(n * KC + k) * 34 + to * 2];
                acc[n][0][0] = fmaf(w.x, h.x, acc[n][0][0]);
                acc[n][0][1] = fmaf(w.x, h.y, acc[n][0][1]);
                acc[n][0][2] = fmaf(w.x, h.z, acc[n][0][2]);
                acc[n][0][3] = fmaf(w.x, h.w, acc[n][0][3]);
                acc[n][1][0] = fmaf(w.y, h.x, acc[n][1][0]);
                acc[n][1][1] = fmaf(w.y, h.y, acc[n][1][1]);
                acc[n][1][2] = fmaf(w.y, h.z, acc[n][1][2]);
                acc[n][1][3] = fmaf(w.y, h.w, acc[n][1][3]);
            }
        }
        if (more) {  // writes go to the OTHER buffer; no race with readers of cur
            const int nxt = cur ^ 1;
            #pragma unroll
            for (int i = 0; i < 8; i++) w_lds[nxt][(wn * KC + wkq) * 34 + woq * 8 + i] = wreg[i];
            #pragma unroll
            for (int i = 0; i < 4; i++) h_lds[nxt][(hk + i) * 68 + hb] = hreg[i];
        }
        __syncthreads();
    }

    // --- epilogue: 4-bank combine + bias + activation ---
    float4 cf[4];
    #pragma unroll
    for (int j = 0; j < 4; j++) cf[j] = *(const float4*)&coef[(b0 + tb * 4 + j) * 4];

    #pragma unroll
    for (int oo = 0; oo < 2; oo++) {
        int o = o0 + to * 2 + oo;
        if (o < O) {
            float bs0 = bias[0 * O + o];
            float bs1 = bias[1 * O + o];
            float bs2 = bias[2 * O + o];
            float bs3 = bias[3 * O + o];
            #pragma unroll
            for (int j = 0; j < 4; j++) {
                int b = b0 + tb * 4 + j;
                float v = cf[j].x * (acc[0][oo][j] + bs0)
                        + cf[j].y * (acc[1][oo][j] + bs1)
                        + cf[j].z * (acc[2][oo][j] + bs2)
                        + cf[j].w * (acc[3][oo][j] + bs3);
                if (ELU) v = (v > 0.f) ? v : expm1f(v);
                Hout[(size_t)b * O + o] = v;
            }
        }
    }
}

extern "C" void kernel_launch(void* const* d_in, const int* in_sizes, int n_in,
                              void* d_out, int out_size, void* d_ws, size_t ws_size,
                              hipStream_t stream) {
    (void)in_sizes; (void)n_in; (void)out_size; (void)ws_size;
    const float* x  = (const float*)d_in[0];
    const float* W0 = (const float*)d_in[1];
    const float* W1 = (const float*)d_in[2];
    const float* W2 = (const float*)d_in[3];
    const float* b0 = (const float*)d_in[4];
    const float* b1 = (const float*)d_in[5];
    const float* b2 = (const float*)d_in[6];
    float* out = (float*)d_out;

    float* ws   = (float*)d_ws;
    float* coef = ws;                      // 1024*4 floats
    float* H1   = ws + 4096;               // 1024*512 floats
    float* H2   = H1 + 1024 * 512;         // 1024*512 floats

    coef_kernel<<<dim3(4), dim3(256), 0, stream>>>(x, coef);
    // L0: (4,512,342) @ x[:, :342]  -> H1 (1024,512), ELU
    layer_kernel<true ><<<dim3(16, 16), dim3(256), 0, stream>>>(W0, b0, x,  343, 342, 512, coef, H1);
    // L1: (4,512,512) @ H1 -> H2 (1024,512), ELU
    layer_kernel<true ><<<dim3(16, 16), dim3(256), 0, stream>>>(W1, b1, H1, 512, 512, 512, coef, H2);
    // L2: (4,311,512) @ H2 -> out (1024,311), no activation
    layer_kernel<false><<<dim3(10, 16), dim3(256), 0, stream>>>(W2, b2, H2, 512, 512, 311, coef, out);
}

// Round 2
// 131.874 us; speedup vs baseline: 1.6598x; 1.6598x over previous
//
#include <hip/hip_runtime.h>
#include <math.h>

typedef short bf16x8 __attribute__((ext_vector_type(8)));
typedef float f32x16 __attribute__((ext_vector_type(16)));

__device__ __forceinline__ unsigned short f2bf(float f) {
    union { float f; unsigned u; } x; x.f = f;
    unsigned r = x.u + 0x7FFFu + ((x.u >> 16) & 1u);
    return (unsigned short)(r >> 16);
}

// Per-sample Catmull-Rom coefficients (bank order) + x -> bf16 (K 342 -> pad 352,
// col 342 = 1.0 for bias folding) + constant tails of H1b/H2b (col 512 = 1.0).
__global__ __launch_bounds__(256) void prep_kernel(
    const float* __restrict__ x, float* __restrict__ coef,
    unsigned short* __restrict__ xb, unsigned short* __restrict__ H1b,
    unsigned short* __restrict__ H2b)
{
    const int b = blockIdx.x, t = threadIdx.x;
    for (int k = t; k < 352; k += 256) {
        unsigned short v;
        if (k < 342)      v = f2bf(x[b * 343 + k]);
        else if (k == 342) v = 0x3F80;  // 1.0 bf16 (bias column)
        else              v = 0;
        xb[b * 352 + k] = v;
    }
    if (t >= 64 && t < 80) {
        int j = t - 64;
        H1b[b * 528 + 512 + j] = (j == 0) ? 0x3F80 : 0;
    }
    if (t >= 96 && t < 112) {
        int j = t - 96;
        H2b[b * 528 + 512 + j] = (j == 0) ? 0x3F80 : 0;
    }
    if (t == 0) {
        float phase = x[b * 343 + 342];
        float ps = 4.0f * phase;
        int k1 = (int)ps;
        float mu = ps - (float)k1;
        k1 &= 3;
        float mu2 = mu * mu, mu3 = mu2 * mu;
        float c0 = -0.5f * mu3 +        mu2 - 0.5f * mu;
        float c1 =  1.5f * mu3 - 2.5f * mu2 + 1.0f;
        float c2 = -1.5f * mu3 + 2.0f * mu2 + 0.5f * mu;
        float c3 =  0.5f * mu3 - 0.5f * mu2;
        float cc[4];
        cc[(k1 + 3) & 3] = c0;
        cc[k1]           = c1;
        cc[(k1 + 1) & 3] = c2;
        cc[(k1 + 2) & 3] = c3;
        *(float4*)(coef + b * 4) = make_float4(cc[0], cc[1], cc[2], cc[3]);
    }
}

// W* fp32 -> bf16 with K padding and bias folded in as column K.
// W0b: (4,512,352) K=342, col342=b0 ; W1b: (4,512,528) K=512, col512=b1 ;
// W2b: (4,320,528) rows 311..319 zero, col512=b2.
__global__ __launch_bounds__(256) void convw_kernel(
    const float* __restrict__ W0, const float* __restrict__ W1, const float* __restrict__ W2,
    const float* __restrict__ b0, const float* __restrict__ b1, const float* __restrict__ b2,
    unsigned short* __restrict__ W0b, unsigned short* __restrict__ W1b, unsigned short* __restrict__ W2b)
{
    constexpr unsigned S0 = 4u * 512 * 352;
    constexpr unsigned S1 = 4u * 512 * 528;
    constexpr unsigned S2 = 4u * 320 * 528;
    unsigned i = (blockIdx.x * 256u + threadIdx.x) * 4u;
    if (i >= S0 + S1 + S2) return;
    float v[4];
    if (i < S0) {
        unsigned n = i / (512u * 352u), r = i % (512u * 352u);
        unsigned o = r / 352u, k = r % 352u;
        unsigned row = n * 512u + o;
        #pragma unroll
        for (int j = 0; j < 4; ++j) {
            unsigned kk = k + j;
            v[j] = (kk < 342u) ? W0[(size_t)row * 342u + kk]
                 : ((kk == 342u) ? b0[row] : 0.f);
        }
        ushort4 pk; pk.x = f2bf(v[0]); pk.y = f2bf(v[1]); pk.z = f2bf(v[2]); pk.w = f2bf(v[3]);
        *(ushort4*)(W0b + i) = pk;
    } else if (i < S0 + S1) {
        unsigned ii = i - S0;
        unsigned n = ii / (512u * 528u), r = ii % (512u * 528u);
        unsigned o = r / 528u, k = r % 528u;
        unsigned row = n * 512u + o;
        if (k + 3u < 512u) {
            float4 w = *(const float4*)(W1 + (size_t)row * 512u + k);
            v[0] = w.x; v[1] = w.y; v[2] = w.z; v[3] = w.w;
        } else {
            #pragma unroll
            for (int j = 0; j < 4; ++j) {
                unsigned kk = k + j;
                v[j] = (kk < 512u) ? W1[(size_t)row * 512u + kk]
                     : ((kk == 512u) ? b1[row] : 0.f);
            }
        }
        ushort4 pk; pk.x = f2bf(v[0]); pk.y = f2bf(v[1]); pk.z = f2bf(v[2]); pk.w = f2bf(v[3]);
        *(ushort4*)(W1b + ii) = pk;
    } else {
        unsigned ii = i - S0 - S1;
        unsigned n = ii / (320u * 528u), r = ii % (320u * 528u);
        unsigned o = r / 528u, k = r % 528u;
        v[0] = v[1] = v[2] = v[3] = 0.f;
        if (o < 311u) {
            unsigned row = n * 311u + o;
            if (k + 3u < 512u) {
                float4 w = *(const float4*)(W2 + (size_t)row * 512u + k);
                v[0] = w.x; v[1] = w.y; v[2] = w.z; v[3] = w.w;
            } else {
                #pragma unroll
                for (int j = 0; j < 4; ++j) {
                    unsigned kk = k + j;
                    v[j] = (kk < 512u) ? W2[(size_t)row * 512u + kk]
                         : ((kk == 512u) ? b2[row] : 0.f);
                }
            }
        }
        ushort4 pk; pk.x = f2bf(v[0]); pk.y = f2bf(v[1]); pk.z = f2bf(v[2]); pk.w = f2bf(v[3]);
        *(ushort4*)(W2b + ii) = pk;
    }
}

// One wave per block. Wave tile: 32 o x 32 b x 4 banks, mfma_f32_32x32x16_bf16.
// Bias is folded into K (extra 1-column), so epilogue = coef-combine + ELU only.
// A/B frags loaded directly from global (L2-resident); full K unroll, no LDS.
template<bool ELU, bool OUT_BF16, int KP, int OPAD, int KPN>
__global__ __launch_bounds__(64) void layer_mfma(
    const unsigned short* __restrict__ Wb,   // (4, OPAD, KP) bf16
    const unsigned short* __restrict__ Hb,   // (1024, KP) bf16
    const float* __restrict__ coef,          // (1024, 4)
    unsigned short* __restrict__ HoutB,      // (1024, KPN) bf16   [OUT_BF16]
    float* __restrict__ outF,                // (1024, Oreal)      [!OUT_BF16]
    int Oreal)
{
    constexpr int NCH = KP / 16;
    const int lane = threadIdx.x;
    const int m = lane & 31;        // A: o-row ; B: b-col
    const int h = lane >> 5;        // k-half: k = h*8 + j
    const int o0 = blockIdx.x * 32, b0v = blockIdx.y * 32;

    const unsigned short* a0 = Wb + ((size_t)(0 * OPAD + o0 + m) * KP + h * 8);
    const unsigned short* a1 = Wb + ((size_t)(1 * OPAD + o0 + m) * KP + h * 8);
    const unsigned short* a2 = Wb + ((size_t)(2 * OPAD + o0 + m) * KP + h * 8);
    const unsigned short* a3 = Wb + ((size_t)(3 * OPAD + o0 + m) * KP + h * 8);
    const unsigned short* bp = Hb + ((size_t)(b0v + m) * KP + h * 8);

    f32x16 acc0 = {}, acc1 = {}, acc2 = {}, acc3 = {};
    #pragma unroll
    for (int c = 0; c < NCH; ++c) {
        bf16x8 bf  = *(const bf16x8*)(bp + c * 16);
        bf16x8 af0 = *(const bf16x8*)(a0 + c * 16);
        bf16x8 af1 = *(const bf16x8*)(a1 + c * 16);
        bf16x8 af2 = *(const bf16x8*)(a2 + c * 16);
        bf16x8 af3 = *(const bf16x8*)(a3 + c * 16);
        acc0 = __builtin_amdgcn_mfma_f32_32x32x16_bf16(af0, bf, acc0, 0, 0, 0);
        acc1 = __builtin_amdgcn_mfma_f32_32x32x16_bf16(af1, bf, acc1, 0, 0, 0);
        acc2 = __builtin_amdgcn_mfma_f32_32x32x16_bf16(af2, bf, acc2, 0, 0, 0);
        acc3 = __builtin_amdgcn_mfma_f32_32x32x16_bf16(af3, bf, acc3, 0, 0, 0);
    }

    const int b = b0v + m;  // C/D: col = lane&31
    float4 cf = *(const float4*)(coef + b * 4);
    #pragma unroll
    for (int g = 0; g < 4; ++g) {
        float v[4];
        #pragma unroll
        for (int j = 0; j < 4; ++j) {
            int r = g * 4 + j;  // row = (r&3) + 8*(r>>2) + 4*h
            float s = cf.x * acc0[r] + cf.y * acc1[r] + cf.z * acc2[r] + cf.w * acc3[r];
            if (ELU) s = (s > 0.f) ? s : expm1f(s);
            v[j] = s;
        }
        int orow = o0 + 8 * g + 4 * h;
        if (OUT_BF16) {
            ushort4 pk;
            pk.x = f2bf(v[0]); pk.y = f2bf(v[1]); pk.z = f2bf(v[2]); pk.w = f2bf(v[3]);
            *(ushort4*)(HoutB + (size_t)b * KPN + orow) = pk;
        } else {
            #pragma unroll
            for (int j = 0; j < 4; ++j)
                if (orow + j < Oreal) outF[(size_t)b * Oreal + orow + j] = v[j];
        }
    }
}

extern "C" void kernel_launch(void* const* d_in, const int* in_sizes, int n_in,
                              void* d_out, int out_size, void* d_ws, size_t ws_size,
                              hipStream_t stream) {
    (void)in_sizes; (void)n_in; (void)out_size; (void)ws_size;
    const float* x  = (const float*)d_in[0];
    const float* W0 = (const float*)d_in[1];
    const float* W1 = (const float*)d_in[2];
    const float* W2 = (const float*)d_in[3];
    const float* b0 = (const float*)d_in[4];
    const float* b1 = (const float*)d_in[5];
    const float* b2 = (const float*)d_in[6];
    float* out = (float*)d_out;

    char* w = (char*)d_ws;
    float*          coef = (float*)(w + 0);                 //    16384 B
    unsigned short* xb   = (unsigned short*)(w + 16384);    //   720896 B (1024x352)
    unsigned short* H1b  = (unsigned short*)(w + 737280);   //  1081344 B (1024x528)
    unsigned short* H2b  = (unsigned short*)(w + 1818624);  //  1081344 B (1024x528)
    unsigned short* W0b  = (unsigned short*)(w + 2899968);  //  1441792 B (4x512x352)
    unsigned short* W1b  = (unsigned short*)(w + 4341760);  //  2162688 B (4x512x528)
    unsigned short* W2b  = (unsigned short*)(w + 6504448);  //  1351680 B (4x320x528)

    prep_kernel<<<dim3(1024), dim3(256), 0, stream>>>(x, coef, xb, H1b, H2b);
    convw_kernel<<<dim3(2420), dim3(256), 0, stream>>>(W0, W1, W2, b0, b1, b2, W0b, W1b, W2b);

    // L0: (4,512,352bf) x xb -> H1b (ELU, bf16 out)
    layer_mfma<true,  true,  352, 512, 528><<<dim3(16, 32), dim3(64), 0, stream>>>(W0b, xb,  coef, H1b, nullptr, 512);
    // L1: (4,512,528bf) x H1b -> H2b (ELU, bf16 out)
    layer_mfma<true,  true,  528, 512, 528><<<dim3(16, 32), dim3(64), 0, stream>>>(W1b, H1b, coef, H2b, nullptr, 512);
    // L2: (4,320,528bf) x H2b -> out (fp32, O=311)
    layer_mfma<false, false, 528, 320, 528><<<dim3(10, 32), dim3(64), 0, stream>>>(W2b, H2b, coef, nullptr, out, 311);
}

// Round 3
// 106.274 us; speedup vs baseline: 2.0597x; 1.2409x over previous
//
#include <hip/hip_runtime.h>
#include <math.h>

typedef short bf16x8 __attribute__((ext_vector_type(8)));
typedef float f32x16 __attribute__((ext_vector_type(16)));

__device__ __forceinline__ unsigned short f2bf(float f) {
    union { float f; unsigned u; } x; x.f = f;
    unsigned r = x.u + 0x7FFFu + ((x.u >> 16) & 1u);
    return (unsigned short)(r >> 16);
}

// KP0=384 (L0, real K=342+bias), KP1=576 (L1/L2, real K=512+bias). Both /4 waves /16 ksteps.

// coef + x->bf16 (row 384: col342=1.0 bias, rest 0) + H1b/H2b constant tails (cols 512..575).
__global__ __launch_bounds__(256) void prep_kernel(
    const float* __restrict__ x, float* __restrict__ coef,
    unsigned short* __restrict__ xb, unsigned short* __restrict__ H1b,
    unsigned short* __restrict__ H2b)
{
    const int b = blockIdx.x, t = threadIdx.x;
    for (int k = t; k < 384; k += 256) {
        unsigned short v;
        if (k < 342)       v = f2bf(x[b * 343 + k]);
        else if (k == 342) v = 0x3F80;  // 1.0 (bias column)
        else               v = 0;
        xb[b * 384 + k] = v;
    }
    if (t >= 64 && t < 128) {
        int j = t - 64;
        H1b[b * 576 + 512 + j] = (j == 0) ? 0x3F80 : 0;
    }
    if (t >= 128 && t < 192) {
        int j = t - 128;
        H2b[b * 576 + 512 + j] = (j == 0) ? 0x3F80 : 0;
    }
    if (t == 0) {
        float phase = x[b * 343 + 342];
        float ps = 4.0f * phase;
        int k1 = (int)ps;
        float mu = ps - (float)k1;
        k1 &= 3;
        float mu2 = mu * mu, mu3 = mu2 * mu;
        float c0 = -0.5f * mu3 +        mu2 - 0.5f * mu;
        float c1 =  1.5f * mu3 - 2.5f * mu2 + 1.0f;
        float c2 = -1.5f * mu3 + 2.0f * mu2 + 0.5f * mu;
        float c3 =  0.5f * mu3 - 0.5f * mu2;
        float cc[4];
        cc[(k1 + 3) & 3] = c0;
        cc[k1]           = c1;
        cc[(k1 + 1) & 3] = c2;
        cc[(k1 + 2) & 3] = c3;
        *(float4*)(coef + b * 4) = make_float4(cc[0], cc[1], cc[2], cc[3]);
    }
}

// W -> bf16 in MFMA A-fragment-major order:
//   Wf[((n*NOT + ot)*NKS + ks)*512 + (h*32 + m)*8 + j]
// where o = ot*32+m, k = ks*16 + h*8 + j.  Bias folded at k==Kreal; zeros beyond.
__global__ __launch_bounds__(256) void convw_kernel(
    const float* __restrict__ W0, const float* __restrict__ W1, const float* __restrict__ W2,
    const float* __restrict__ b0, const float* __restrict__ b1, const float* __restrict__ b2,
    unsigned short* __restrict__ Wf0, unsigned short* __restrict__ Wf1, unsigned short* __restrict__ Wf2)
{
    constexpr unsigned E0 = 4u * 512 * 384;   // 786432
    constexpr unsigned E1 = 4u * 512 * 576;   // 1179648
    constexpr unsigned E2 = 4u * 320 * 576;   // 737280
    unsigned i = (blockIdx.x * 256u + threadIdx.x) * 4u;
    if (i >= E0 + E1 + E2) return;
    float v[4];
    unsigned n, o, k, NOT, NKS, KPv;
    unsigned short* dst;
    if (i < E0) {
        n = i / (512u * 384u); unsigned r = i % (512u * 384u);
        o = r / 384u; k = r % 384u; NOT = 16; NKS = 24; KPv = 384; dst = Wf0;
        unsigned row = n * 512u + o;
        #pragma unroll
        for (int j = 0; j < 4; ++j) {
            unsigned kk = k + j;
            v[j] = (kk < 342u) ? W0[(size_t)row * 342u + kk] : ((kk == 342u) ? b0[row] : 0.f);
        }
    } else if (i < E0 + E1) {
        unsigned ii = i - E0;
        n = ii / (512u * 576u); unsigned r = ii % (512u * 576u);
        o = r / 576u; k = r % 576u; NOT = 16; NKS = 36; KPv = 576; dst = Wf1;
        unsigned row = n * 512u + o;
        if (k + 3u < 512u) {
            float4 w = *(const float4*)(W1 + (size_t)row * 512u + k);
            v[0] = w.x; v[1] = w.y; v[2] = w.z; v[3] = w.w;
        } else {
            #pragma unroll
            for (int j = 0; j < 4; ++j) {
                unsigned kk = k + j;
                v[j] = (kk < 512u) ? W1[(size_t)row * 512u + kk] : ((kk == 512u) ? b1[row] : 0.f);
            }
        }
    } else {
        unsigned ii = i - E0 - E1;
        n = ii / (320u * 576u); unsigned r = ii % (320u * 576u);
        o = r / 576u; k = r % 576u; NOT = 10; NKS = 36; KPv = 576; dst = Wf2;
        v[0] = v[1] = v[2] = v[3] = 0.f;
        if (o < 311u) {
            unsigned row = n * 311u + o;
            if (k + 3u < 512u) {
                float4 w = *(const float4*)(W2 + (size_t)row * 512u + k);
                v[0] = w.x; v[1] = w.y; v[2] = w.z; v[3] = w.w;
            } else {
                #pragma unroll
                for (int j = 0; j < 4; ++j) {
                    unsigned kk = k + j;
                    v[j] = (kk < 512u) ? W2[(size_t)row * 512u + kk] : ((kk == 512u) ? b2[row] : 0.f);
                }
            }
        }
    }
    (void)KPv;
    unsigned ot = o >> 5, m = o & 31, ks = k >> 4, h = (k >> 3) & 1, j4 = k & 7;
    size_t off = (((size_t)(n * NOT + ot) * NKS + ks) * 64u + h * 32u + m) * 8u + j4;
    ushort4 pk; pk.x = f2bf(v[0]); pk.y = f2bf(v[1]); pk.z = f2bf(v[2]); pk.w = f2bf(v[3]);
    *(ushort4*)(dst + off) = pk;
}

// Block: 256 thr / 4 waves; tile 32o x 32b; wave w owns k-quarter w.
// H tile (32 x KP) staged once in LDS (row stride KP+8 -> odd*16B, conflict-free b128).
// K-loop: 4 coalesced global A-frag loads (frag-major Wf) + 1 ds_read + 4 MFMA. No barriers.
// Epilogue: in-wave coef combine; waves 1..3 dump f32 partials to LDS; wave 0 reduces+ELU+stores.
template<bool ELU, bool OUT_BF16, int KP, int OPAD>
__global__ __launch_bounds__(256) void layer_mfma(
    const unsigned short* __restrict__ Wf,   // frag-major (4, OPAD/32, KP/16, 64, 8)
    const unsigned short* __restrict__ Hb,   // (1024, KP) row-major bf16
    const float* __restrict__ coef,          // (1024, 4)
    unsigned short* __restrict__ HoutB,      // (1024, 576) bf16   [OUT_BF16]
    float* __restrict__ outF,                // (1024, Oreal) f32  [!OUT_BF16]
    int Oreal)
{
    constexpr int NOT = OPAD / 32, NKS = KP / 16, KSQ = NKS / 4, RS = KP + 8;
    __shared__ unsigned short hs[32 * RS];

    const int tid = threadIdx.x, lane = tid & 63, w = tid >> 6;
    const int ot = blockIdx.x, b0 = blockIdx.y * 32;

    // --- stage H tile (32 rows x KP cols) ---
    constexpr int CPT = (32 * KP / 8) / 256;   // 16B chunks per thread (6 or 9)
    #pragma unroll
    for (int c = 0; c < CPT; ++c) {
        int idx = c * 256 + tid;
        int r = idx / (KP / 8), col = idx % (KP / 8);
        *(bf16x8*)&hs[r * RS + col * 8] = *(const bf16x8*)(Hb + (size_t)(b0 + r) * KP + col * 8);
    }
    __syncthreads();

    const int m = lane & 31, h = lane >> 5;
    const unsigned short* hrow = &hs[m * RS + h * 8 + w * KSQ * 16];
    const unsigned short* wbase = Wf + (size_t)ot * NKS * 512 + (size_t)w * KSQ * 512 + lane * 8;
    const size_t nstr = (size_t)NOT * NKS * 512;

    f32x16 acc0 = {}, acc1 = {}, acc2 = {}, acc3 = {};
    #pragma unroll
    for (int s = 0; s < KSQ; ++s) {
        bf16x8 bfr = *(const bf16x8*)(hrow + s * 16);
        bf16x8 a0 = *(const bf16x8*)(wbase + (size_t)s * 512);
        bf16x8 a1 = *(const bf16x8*)(wbase + nstr + (size_t)s * 512);
        bf16x8 a2 = *(const bf16x8*)(wbase + 2 * nstr + (size_t)s * 512);
        bf16x8 a3 = *(const bf16x8*)(wbase + 3 * nstr + (size_t)s * 512);
        acc0 = __builtin_amdgcn_mfma_f32_32x32x16_bf16(a0, bfr, acc0, 0, 0, 0);
        acc1 = __builtin_amdgcn_mfma_f32_32x32x16_bf16(a1, bfr, acc1, 0, 0, 0);
        acc2 = __builtin_amdgcn_mfma_f32_32x32x16_bf16(a2, bfr, acc2, 0, 0, 0);
        acc3 = __builtin_amdgcn_mfma_f32_32x32x16_bf16(a3, bfr, acc3, 0, 0, 0);
    }

    // --- in-wave coef combine (verified round-2 math) ---
    const int b = b0 + m;
    float4 cf = *(const float4*)(coef + b * 4);
    float sv[16];
    #pragma unroll
    for (int r = 0; r < 16; ++r)
        sv[r] = cf.x * acc0[r] + cf.y * acc1[r] + cf.z * acc2[r] + cf.w * acc3[r];

    __syncthreads();                       // everyone done reading hs
    float* red = (float*)hs;               // 3 planes x 1024 f32 = 12KB (fits)
    if (w > 0) {
        #pragma unroll
        for (int g = 0; g < 4; ++g)
            #pragma unroll
            for (int j = 0; j < 4; ++j) {
                int row = 8 * g + 4 * h + j;
                red[(w - 1) * 1024 + row * 32 + m] = sv[g * 4 + j];
            }
    }
    __syncthreads();
    if (w == 0) {
        #pragma unroll
        for (int g = 0; g < 4; ++g) {
            float vv[4];
            #pragma unroll
            for (int j = 0; j < 4; ++j) {
                int row = 8 * g + 4 * h + j;
                float v = sv[g * 4 + j] + red[row * 32 + m]
                        + red[1024 + row * 32 + m] + red[2048 + row * 32 + m];
                if (ELU) v = (v > 0.f) ? v : expm1f(v);
                vv[j] = v;
            }
            int orow = ot * 32 + 8 * g + 4 * h;
            if (OUT_BF16) {
                ushort4 pk;
                pk.x = f2bf(vv[0]); pk.y = f2bf(vv[1]); pk.z = f2bf(vv[2]); pk.w = f2bf(vv[3]);
                *(ushort4*)(HoutB + (size_t)b * 576 + orow) = pk;
            } else {
                #pragma unroll
                for (int j = 0; j < 4; ++j)
                    if (orow + j < Oreal) outF[(size_t)b * Oreal + orow + j] = vv[j];
            }
        }
    }
}

extern "C" void kernel_launch(void* const* d_in, const int* in_sizes, int n_in,
                              void* d_out, int out_size, void* d_ws, size_t ws_size,
                              hipStream_t stream) {
    (void)in_sizes; (void)n_in; (void)out_size; (void)ws_size;
    const float* x  = (const float*)d_in[0];
    const float* W0 = (const float*)d_in[1];
    const float* W1 = (const float*)d_in[2];
    const float* W2 = (const float*)d_in[3];
    const float* b0 = (const float*)d_in[4];
    const float* b1 = (const float*)d_in[5];
    const float* b2 = (const float*)d_in[6];
    float* out = (float*)d_out;

    char* wsb = (char*)d_ws;
    float*          coef = (float*)(wsb + 0);                  //   16384 B
    unsigned short* xb   = (unsigned short*)(wsb + 16384);     //  786432 B (1024x384)
    unsigned short* H1b  = (unsigned short*)(wsb + 802816);    // 1179648 B (1024x576)
    unsigned short* H2b  = (unsigned short*)(wsb + 1982464);   // 1179648 B (1024x576)
    unsigned short* Wf0  = (unsigned short*)(wsb + 3162112);   // 1572864 B (4x512x384)
    unsigned short* Wf1  = (unsigned short*)(wsb + 4734976);   // 2359296 B (4x512x576)
    unsigned short* Wf2  = (unsigned short*)(wsb + 7094272);   // 1474560 B (4x320x576)

    prep_kernel<<<dim3(1024), dim3(256), 0, stream>>>(x, coef, xb, H1b, H2b);
    convw_kernel<<<dim3(2640), dim3(256), 0, stream>>>(W0, W1, W2, b0, b1, b2, Wf0, Wf1, Wf2);

    // L0: (4,512,384) x xb -> H1b (ELU, bf16)
    layer_mfma<true,  true,  384, 512><<<dim3(16, 32), dim3(256), 0, stream>>>(Wf0, xb,  coef, H1b, nullptr, 512);
    // L1: (4,512,576) x H1b -> H2b (ELU, bf16)
    layer_mfma<true,  true,  576, 512><<<dim3(16, 32), dim3(256), 0, stream>>>(Wf1, H1b, coef, H2b, nullptr, 512);
    // L2: (4,320,576) x H2b -> out (f32, O=311)
    layer_mfma<false, false, 576, 320><<<dim3(10, 32), dim3(256), 0, stream>>>(Wf2, H2b, coef, nullptr, out, 311);
}